// Round 11
// baseline (178.237 us; speedup 1.0000x reference)
//
#include <hip/hip_runtime.h>
#include <hip/hip_bf16.h>

// Round 11: 32q/wave at 2 independent blocks/CU.
//  The r7 wall is the LDS pipe: every wave reads the full 16KB K+V tile, and
//  16 waves/CU puts ~55-62us on LDS alone. 32q/wave halves per-unit-work LDS
//  traffic (floor ~30us). Prior 32q attempts failed for fixable reasons:
//  r5 = ONE block/CU (8 waves barrier-lockstep); r6 = parity spill.
//  This round: BQ=128, 256 thr (4 waves x 32q, two reg-shared 16q subtiles),
//  grid 512 -> TWO independently-barriered blocks/CU (decoupled stalls).
//  Components all proven: b64+XOR-swizzle PV (r7; r10's b128 interleave
//  regressed +4.2M conflict cycles -> reverted), fixed-m softmax (r6/r7),
//  global-mask fma (r10, neutral), dbuf + reg prefetch + 1 barrier (r4+).
//  launch_bounds(256,2): VGPR cap 256 -- no artificial squeeze (r9 lesson);
//  occupancy is LDS-set (36.9KB -> 2 blocks), not VGPR-set.

typedef __attribute__((ext_vector_type(8))) short bf16x8;
typedef __attribute__((ext_vector_type(4))) short bf16x4;
typedef __attribute__((ext_vector_type(4))) float f32x4;

#define B_ 2
#define S_ 2048
#define H_ 16
#define D_ 64
#define BQ 128
#define BK 64
#define NT (S_ / BK)
#define LDK 72                 // padded LDS row (144 B)
#define ROWSZ (H_ * D_)        // 1024 floats between s rows

#define LOG2E  1.44269504088896340736f
#define SCALE2 (0.125f * LOG2E)

__device__ __forceinline__ unsigned pack2(float a, float b) {
    union { __hip_bfloat162 h; unsigned u; } x;
    x.h = __float22bfloat162_rn(make_float2(a, b));   // v_cvt_pk_bf16_f32
    return x.u;
}

__device__ __forceinline__ float fexp2(float x) {
#if __has_builtin(__builtin_amdgcn_exp2f)
    return __builtin_amdgcn_exp2f(x);
#else
    return __expf(x * 0.69314718055994531f);
#endif
}

__device__ __forceinline__ f32x4 mfma16(bf16x4 a, bf16x4 b, f32x4 c) {
#if __has_builtin(__builtin_amdgcn_mfma_f32_16x16x16bf16_1k)
    return __builtin_amdgcn_mfma_f32_16x16x16bf16_1k(a, b, c, 0, 0, 0);
#else
    bf16x8 a8 = {a[0], a[1], a[2], a[3], 0, 0, 0, 0};
    bf16x8 b8 = {b[0], b[1], b[2], b[3], 0, 0, 0, 0};
    return __builtin_amdgcn_mfma_f32_16x16x32_bf16(a8, b8, c, 0, 0, 0);
#endif
}

__global__ __launch_bounds__(256, 2)
void fattn_kernel(const float* __restrict__ qg,
                  const float* __restrict__ kg,
                  const float* __restrict__ vg,
                  const float* __restrict__ maskg,
                  float* __restrict__ outg)
{
    __shared__ __attribute__((aligned(16))) ushort Ks[2][BK * LDK];  // row=key, col=d
    __shared__ __attribute__((aligned(16))) ushort Vt[2][D_ * LDK];  // row=d, XOR-swizzled granules

    const int qt = blockIdx.x, h = blockIdx.y, b = blockIdx.z;
    const int tid = threadIdx.x;
    const int w = tid >> 6, lane = tid & 63, g = lane >> 4, l15 = lane & 15;
    const int gh = g >> 1, glo = g & 1, h3 = l15 >> 3;

    // ---- Q fragments, two 16q subtiles (B-operand x32), scale folded ----
    bf16x8 qf[2][2];
#pragma unroll
    for (int s = 0; s < 2; ++s) {
        const int qrow = qt * BQ + w * 32 + s * 16 + l15;
        const float* qp = qg + (size_t)(b * S_ + qrow) * ROWSZ + h * D_;
#pragma unroll
        for (int half = 0; half < 2; ++half) {
            float4 f0 = *(const float4*)(qp + half * 32 + g * 8);
            float4 f1 = *(const float4*)(qp + half * 32 + g * 8 + 4);
            union { bf16x8 v; uint4 u; } x;
            x.u = make_uint4(pack2(f0.x * SCALE2, f0.y * SCALE2),
                             pack2(f0.z * SCALE2, f0.w * SCALE2),
                             pack2(f1.x * SCALE2, f1.y * SCALE2),
                             pack2(f1.z * SCALE2, f1.w * SCALE2));
            qf[s][half] = x.v;
        }
    }

    // staging maps (256 threads stage the 64x64 K and V tiles)
    const int skey16 = tid >> 4;        // 0..15: K rows skey16 + 16p
    const int sd4    = (tid & 15) * 4;  // K d-offset (float4)
    const int svd    = lane;            // V: d = lane; granules G = 2w+p
    const int esw    = (lane >> 3) & 7; // V-store swizzle term

    const size_t kvbase = (size_t)b * S_ * ROWSZ + h * D_;
    const float* maskb = maskg + (size_t)b * S_;

    float4 kpre[4];
    float  vpre[16];
    auto prefetch = [&](int kt) {
        const float* kb = kg + kvbase + (size_t)kt * BK * ROWSZ;
#pragma unroll
        for (int p = 0; p < 4; ++p)
            kpre[p] = *(const float4*)(kb + (size_t)(skey16 + 16 * p) * ROWSZ + sd4);
        const float* vb = vg + kvbase + (size_t)kt * BK * ROWSZ + svd;
#pragma unroll
        for (int i = 0; i < 16; ++i)
            vpre[i] = vb[(size_t)(16 * w + i) * ROWSZ];
    };
    auto stage = [&](int buf) {
#pragma unroll
        for (int p = 0; p < 4; ++p)
            *(uint2*)&Ks[buf][(skey16 + 16 * p) * LDK + sd4] =
                make_uint2(pack2(kpre[p].x, kpre[p].y), pack2(kpre[p].z, kpre[p].w));
#pragma unroll
        for (int p = 0; p < 2; ++p) {
            const int G = 2 * w + p;
            *(uint4*)&Vt[buf][svd * LDK + ((G ^ esw) * 8)] =
                make_uint4(pack2(vpre[8 * p + 0], vpre[8 * p + 1]),
                           pack2(vpre[8 * p + 2], vpre[8 * p + 3]),
                           pack2(vpre[8 * p + 4], vpre[8 * p + 5]),
                           pack2(vpre[8 * p + 6], vpre[8 * p + 7]));
        }
    };

    float l_r[2] = {0.0f, 0.0f};        // per-lane (q=l15) partial denominators
    f32x4 o_acc[2][4];
#pragma unroll
    for (int s = 0; s < 2; ++s)
#pragma unroll
        for (int t = 0; t < 4; ++t) o_acc[s][t] = (f32x4){0.f, 0.f, 0.f, 0.f};

    prefetch(0);
    stage(0);
    __syncthreads();

    const int koff  = l15 * LDK + g * 8;
    const int vbase = l15 * LDK + glo * 4;

    for (int kt = 0; kt < NT; ++kt) {
        const int cur = kt & 1;
        if (kt + 1 < NT) prefetch(kt + 1);   // loads in flight across compute

        // ---- St = K Q^T (C=0); kf fragments shared across both subtiles ----
        const ushort* ks = Ks[cur];
        float sv[2][4][4];
#pragma unroll
        for (int t = 0; t < 4; ++t) {
            bf16x8 kf0 = *(const bf16x8*)&ks[t * 16 * LDK + koff];
            bf16x8 kf1 = *(const bf16x8*)&ks[t * 16 * LDK + koff + 32];
#pragma unroll
            for (int s = 0; s < 2; ++s) {
                f32x4 acc = (f32x4){0.f, 0.f, 0.f, 0.f};
                acc = __builtin_amdgcn_mfma_f32_16x16x32_bf16(kf0, qf[s][0], acc, 0, 0, 0);
                acc = __builtin_amdgcn_mfma_f32_16x16x32_bf16(kf1, qf[s][1], acc, 0, 0, 0);
                sv[s][t][0] = acc[0]; sv[s][t][1] = acc[1];
                sv[s][t][2] = acc[2]; sv[s][t][3] = acc[3];
            }
        }

        // ---- fixed-base softmax; mask loaded once, shared by both subtiles ----
        bf16x4 pf[2][4];
        float rs0 = 0.f, rs1 = 0.f;
#pragma unroll
        for (int t = 0; t < 4; ++t) {
            const f32x4 mk = *(const f32x4*)(maskb + kt * BK + t * 16 + g * 4);
            float a0 = fexp2(fmaf(mk[0], LOG2E, sv[0][t][0]));
            float a1 = fexp2(fmaf(mk[1], LOG2E, sv[0][t][1]));
            float a2 = fexp2(fmaf(mk[2], LOG2E, sv[0][t][2]));
            float a3 = fexp2(fmaf(mk[3], LOG2E, sv[0][t][3]));
            rs0 += (a0 + a1) + (a2 + a3);
            union { bf16x4 v; uint2 u; } xa;
            xa.u = make_uint2(pack2(a0, a1), pack2(a2, a3));
            pf[0][t] = xa.v;
            float b0 = fexp2(fmaf(mk[0], LOG2E, sv[1][t][0]));
            float b1 = fexp2(fmaf(mk[1], LOG2E, sv[1][t][1]));
            float b2 = fexp2(fmaf(mk[2], LOG2E, sv[1][t][2]));
            float b3 = fexp2(fmaf(mk[3], LOG2E, sv[1][t][3]));
            rs1 += (b0 + b1) + (b2 + b3);
            union { bf16x4 v; uint2 u; } xb;
            xb.u = make_uint2(pack2(b0, b1), pack2(b2, b3));
            pf[1][t] = xb.v;
        }
        l_r[0] += rs0;
        l_r[1] += rs1;

        // ---- O^T += V^T P^T : b64 reads (r7-proven), vf shared by subtiles ----
        const ushort* vt = Vt[cur];
#pragma unroll
        for (int t2 = 0; t2 < 4; ++t2) {
            const int e = (2 * t2 + h3) & 7;          // (d>>3)&7 for d=t2*16+l15
#pragma unroll
            for (int c = 0; c < 4; ++c) {
                const int physu = (2 * c + gh) ^ e;
                bf16x4 vf = *(const bf16x4*)&vt[t2 * 16 * LDK + vbase + physu * 8];
                o_acc[0][t2] = mfma16(vf, pf[0][c], o_acc[0][t2]);
                o_acc[1][t2] = mfma16(vf, pf[1][c], o_acc[1][t2]);
            }
        }

        if (kt + 1 < NT) stage(cur ^ 1);    // vmcnt drain lands post-compute
        __syncthreads();                    // single barrier per tile
    }

    // ---- epilogue: per-subtile l reduce, normalize, store fp32 ----
#pragma unroll
    for (int s = 0; s < 2; ++s) {
        float lv = l_r[s];
        lv += __shfl_xor(lv, 16);
        lv += __shfl_xor(lv, 32);
        const float inv = 1.0f / lv;
        const int qrow = qt * BQ + w * 32 + s * 16 + l15;
        float* op = outg + (size_t)(b * S_ + qrow) * ROWSZ + h * D_;
#pragma unroll
        for (int t2 = 0; t2 < 4; ++t2)
#pragma unroll
            for (int r = 0; r < 4; ++r)
                op[t2 * 16 + g * 4 + r] = o_acc[s][t2][r] * inv;
    }
}

extern "C" void kernel_launch(void* const* d_in, const int* in_sizes, int n_in,
                              void* d_out, int out_size, void* d_ws, size_t ws_size,
                              hipStream_t stream) {
    dim3 grid(S_ / BQ, H_, B_);   // (16,16,2) = 512 blocks, 2 per CU
    fattn_kernel<<<grid, dim3(256), 0, stream>>>(
        (const float*)d_in[0], (const float*)d_in[1], (const float*)d_in[2],
        (const float*)d_in[3], (float*)d_out);
}

// Round 12
// 159.309 us; speedup vs baseline: 1.1188x; 1.1188x over previous
//
#include <hip/hip_runtime.h>
#include <hip/hip_bf16.h>

// Round 12: pre-converted bf16 K / V^T in d_ws + global_load_lds staging.
//  r7's staging path (10 fp32 loads -> 8 pack2 -> 3 ds_write per tile/thread,
//  conversion repeated by all 16 q-blocks sharing each (b,h)) is replaced by:
//   - prep_k: K fp32 [b,s,h,d] -> bf16 [b,h,kt,chunk], chunk=key*8+(dc^(key&7))
//   - prep_v: V fp32 -> bf16 transposed [b,h,d,kt,slot], slot holds keys
//     (slot^(d&7))*8..+7  (XOR bank swizzle baked into the GLOBAL layout)
//   - main: staging = 2 global_load_lds(16B)/wave/tile into PACKED LDS
//     (deposit = wave-uniform base + lane*16; swizzle pre-applied so linear
//     lane order IS the conflict-free layout).
//  Fragment reads on packed LDS bank-audited: QK b128 phases hit bank-group
//  g^(l15&7) -> all distinct; PV b64 2-way (free, m136).
//  Compute core (S^T MFMA, fixed-m softmax, global-mask fma, dbuf, 1
//  barrier/tile) = r7/r10 proven. Fallback = r7 verbatim if ws too small.

typedef __attribute__((ext_vector_type(8))) short bf16x8;
typedef __attribute__((ext_vector_type(4))) short bf16x4;
typedef __attribute__((ext_vector_type(4))) float f32x4;

#define B_ 2
#define S_ 2048
#define H_ 16
#define D_ 64
#define BQ 128
#define BK 64
#define NT (S_ / BK)
#define LDK 72                 // fallback kernel only
#define ROWSZ (H_ * D_)

#define LOG2E  1.44269504088896340736f
#define SCALE2 (0.125f * LOG2E)

__device__ __forceinline__ unsigned pack2(float a, float b) {
    union { __hip_bfloat162 h; unsigned u; } x;
    x.h = __float22bfloat162_rn(make_float2(a, b));   // v_cvt_pk_bf16_f32
    return x.u;
}

__device__ __forceinline__ float fexp2(float x) {
#if __has_builtin(__builtin_amdgcn_exp2f)
    return __builtin_amdgcn_exp2f(x);
#else
    return __expf(x * 0.69314718055994531f);
#endif
}

__device__ __forceinline__ f32x4 mfma16(bf16x4 a, bf16x4 b, f32x4 c) {
#if __has_builtin(__builtin_amdgcn_mfma_f32_16x16x16bf16_1k)
    return __builtin_amdgcn_mfma_f32_16x16x16bf16_1k(a, b, c, 0, 0, 0);
#else
    bf16x8 a8 = {a[0], a[1], a[2], a[3], 0, 0, 0, 0};
    bf16x8 b8 = {b[0], b[1], b[2], b[3], 0, 0, 0, 0};
    return __builtin_amdgcn_mfma_f32_16x16x32_bf16(a8, b8, c, 0, 0, 0);
#endif
}

__device__ __forceinline__ void gll16(const ushort* g, ushort* l) {
    __builtin_amdgcn_global_load_lds(
        (const __attribute__((address_space(1))) void*)g,
        (__attribute__((address_space(3))) void*)l, 16, 0, 0);
}

// ---- pre-pass: K fp32 [b,s,h,d] -> bf16 [b,h,kt, phys-chunk] ----
// phys = key*8 + (dc ^ (key&7)); one 16B chunk per thread; reads/writes coalesced.
__global__ __launch_bounds__(256)
void prep_k(const float* __restrict__ kg, ushort* __restrict__ kb) {
    const int cid  = blockIdx.x * 256 + threadIdx.x;   // 524288 chunks total
    const int phys = cid & 511;
    const int tile = cid >> 9;            // (b*H+h)*NT + kt
    const int key  = phys >> 3;
    const int dc   = (phys & 7) ^ (key & 7);
    const int kt   = tile & (NT - 1);
    const int bh   = tile >> 5;
    const int h    = bh & (H_ - 1);
    const int b    = bh >> 4;
    const float* src = kg + ((size_t)(b * S_ + kt * BK + key) * H_ + h) * D_ + dc * 8;
    float4 f0 = *(const float4*)src;
    float4 f1 = *(const float4*)(src + 4);
    ((uint4*)kb)[cid] = make_uint4(pack2(f0.x, f0.y), pack2(f0.z, f0.w),
                                   pack2(f1.x, f1.y), pack2(f1.z, f1.w));
}

// ---- pre-pass: V fp32 [b,s,h,d] -> bf16 V^T [b,h,d, kt, slot] ----
// chunk (d,kt,slot) holds keys kt*64 + (slot^(d&7))*8 .. +7 (swizzle baked in).
__global__ __launch_bounds__(256)
void prep_v(const float* __restrict__ vg, ushort* __restrict__ vb) {
    __shared__ ushort T[BK][80];          // [key][d], padded row
    const int tile = blockIdx.x;          // (b*H+h)*NT + kt
    const int kt = tile & (NT - 1);
    const int bh = tile >> 5;
    const int h  = bh & (H_ - 1);
    const int b  = bh >> 4;
    const int t  = threadIdx.x;
    {
        const int key = t >> 2, d0 = (t & 3) * 16;
        const float* src = vg + ((size_t)(b * S_ + kt * BK + key) * H_ + h) * D_ + d0;
        float4 a0 = *(const float4*)(src);
        float4 a1 = *(const float4*)(src + 4);
        float4 a2 = *(const float4*)(src + 8);
        float4 a3 = *(const float4*)(src + 12);
        *(uint4*)&T[key][d0]     = make_uint4(pack2(a0.x, a0.y), pack2(a0.z, a0.w),
                                              pack2(a1.x, a1.y), pack2(a1.z, a1.w));
        *(uint4*)&T[key][d0 + 8] = make_uint4(pack2(a2.x, a2.y), pack2(a2.z, a2.w),
                                              pack2(a3.x, a3.y), pack2(a3.z, a3.w));
    }
    __syncthreads();
    const size_t obase = (size_t)bh * D_ * (S_ / 8);   // uint4 units
#pragma unroll
    for (int i = 0; i < 2; ++i) {
        const int c = 2 * t + i;          // 0..511
        const int d = c >> 3, slot = c & 7;
        const int k0 = (slot ^ (d & 7)) * 8;
        unsigned p0 = (unsigned)T[k0 + 0][d] | ((unsigned)T[k0 + 1][d] << 16);
        unsigned p1 = (unsigned)T[k0 + 2][d] | ((unsigned)T[k0 + 3][d] << 16);
        unsigned p2 = (unsigned)T[k0 + 4][d] | ((unsigned)T[k0 + 5][d] << 16);
        unsigned p3 = (unsigned)T[k0 + 6][d] | ((unsigned)T[k0 + 7][d] << 16);
        ((uint4*)vb)[obase + (size_t)d * (S_ / 8) + kt * 8 + slot] =
            make_uint4(p0, p1, p2, p3);
    }
}

// ---- main: DMA-staged flash attention ----
__global__ __launch_bounds__(512, 4)
void fattn_gll(const float* __restrict__ qg,
               const ushort* __restrict__ kb,
               const ushort* __restrict__ vb,
               const float* __restrict__ maskg,
               float* __restrict__ outg)
{
    __shared__ __attribute__((aligned(16))) ushort Ks[2][BK * D_];  // packed swizzled
    __shared__ __attribute__((aligned(16))) ushort Vt[2][D_ * BK];

    const int qt = blockIdx.x, h = blockIdx.y, b = blockIdx.z;
    const int tid = threadIdx.x;
    const int w = tid >> 6, lane = tid & 63, g = lane >> 4, l15 = lane & 15;
    const int gh = g >> 1, glo = g & 1, e7 = l15 & 7;

    // ---- Q fragment (B-operand x32), scale folded (r7) ----
    const int qrow = qt * BQ + w * 16 + l15;
    const float* qp = qg + (size_t)(b * S_ + qrow) * ROWSZ + h * D_;
    bf16x8 qf[2];
#pragma unroll
    for (int half = 0; half < 2; ++half) {
        float4 f0 = *(const float4*)(qp + half * 32 + g * 8);
        float4 f1 = *(const float4*)(qp + half * 32 + g * 8 + 4);
        union { bf16x8 v; uint4 u; } x;
        x.u = make_uint4(pack2(f0.x * SCALE2, f0.y * SCALE2),
                         pack2(f0.z * SCALE2, f0.w * SCALE2),
                         pack2(f1.x * SCALE2, f1.y * SCALE2),
                         pack2(f1.z * SCALE2, f1.w * SCALE2));
        qf[half] = x.v;
    }

    // ---- DMA staging addresses (all swizzle pre-baked in global layout) ----
    const ushort* ktile0 = kb + (size_t)((b * H_ + h) * NT) * (BK * D_)
                              + (size_t)(w * 64 + lane) * 8;          // +4096/tile
    const ushort* vrow0  = vb + ((size_t)(b * H_ + h) * D_ + (w * 8 + (lane >> 3))) * S_
                              + (lane & 7) * 8;                       // +64/tile
    const float* maskb = maskg + (size_t)b * S_;

    float l_r = 0.0f;
    f32x4 o_acc[4];
#pragma unroll
    for (int t = 0; t < 4; ++t) o_acc[t] = (f32x4){0.f, 0.f, 0.f, 0.f};

    // prologue
    gll16(ktile0, &Ks[0][w * 512]);
    gll16(vrow0,  &Vt[0][w * 512]);
    __syncthreads();

    for (int kt = 0; kt < NT; ++kt) {
        const int cur = kt & 1;
        if (kt + 1 < NT) {                 // async prefetch into other buffer
            gll16(ktile0 + (size_t)(kt + 1) * (BK * D_), &Ks[cur ^ 1][w * 512]);
            gll16(vrow0  + (size_t)(kt + 1) * 64,        &Vt[cur ^ 1][w * 512]);
        }

        // ---- St = K Q^T (C=0); packed-swizzled reads: chunk=key*8+(dc^key&7) ----
        const ushort* ks = Ks[cur];
        float sv[4][4];
#pragma unroll
        for (int t = 0; t < 4; ++t) {
            const int rb = (t * 16 + l15) * 64;         // key&7 == l15&7
            bf16x8 kf0 = *(const bf16x8*)&ks[rb + ((g       ^ e7) * 8)];
            bf16x8 kf1 = *(const bf16x8*)&ks[rb + (((g + 4) ^ e7) * 8)];
            f32x4 acc = (f32x4){0.f, 0.f, 0.f, 0.f};
            acc = __builtin_amdgcn_mfma_f32_16x16x32_bf16(kf0, qf[0], acc, 0, 0, 0);
            acc = __builtin_amdgcn_mfma_f32_16x16x32_bf16(kf1, qf[1], acc, 0, 0, 0);
            sv[t][0] = acc[0]; sv[t][1] = acc[1]; sv[t][2] = acc[2]; sv[t][3] = acc[3];
        }

        // ---- fixed-base softmax, mask from global (fma into exp2) ----
        float rs = 0.f;
        bf16x4 pf[4];
#pragma unroll
        for (int t = 0; t < 4; ++t) {
            const f32x4 mk = *(const f32x4*)(maskb + kt * BK + t * 16 + g * 4);
            float p0 = fexp2(fmaf(mk[0], LOG2E, sv[t][0]));
            float p1 = fexp2(fmaf(mk[1], LOG2E, sv[t][1]));
            float p2 = fexp2(fmaf(mk[2], LOG2E, sv[t][2]));
            float p3 = fexp2(fmaf(mk[3], LOG2E, sv[t][3]));
            rs += (p0 + p1) + (p2 + p3);
            union { bf16x4 v; uint2 u; } x;
            x.u = make_uint2(pack2(p0, p1), pack2(p2, p3));
            pf[t] = x.v;
        }
        l_r += rs;

        // ---- O^T += V^T P^T; chunk (d, s) holds keys (s^(d&7))*8.. ----
        const ushort* vt = Vt[cur];
#pragma unroll
        for (int t2 = 0; t2 < 4; ++t2) {
            const int rb = (t2 * 16 + l15) * 64;        // d&7 == l15&7
#pragma unroll
            for (int c = 0; c < 4; ++c) {
                const int s = (2 * c + gh) ^ e7;
                bf16x4 vf = *(const bf16x4*)&vt[rb + s * 8 + glo * 4];
                o_acc[t2] = mfma16(vf, pf[c], o_acc[t2]);
            }
        }

        __syncthreads();    // drains prefetch vmcnt + releases cur
    }

    // ---- epilogue ----
    l_r += __shfl_xor(l_r, 16);
    l_r += __shfl_xor(l_r, 32);
    const float inv = 1.0f / l_r;
    float* op = outg + (size_t)(b * S_ + qrow) * ROWSZ + h * D_;
#pragma unroll
    for (int t2 = 0; t2 < 4; ++t2)
#pragma unroll
        for (int r = 0; r < 4; ++r)
            op[t2 * 16 + g * 4 + r] = o_acc[t2][r] * inv;
}

// ---- fallback: r7 verbatim (81us) for small ws_size ----
__global__ __launch_bounds__(512, 4)
void fattn_fb(const float* __restrict__ qg,
              const float* __restrict__ kg,
              const float* __restrict__ vg,
              const float* __restrict__ maskg,
              float* __restrict__ outg)
{
    __shared__ __attribute__((aligned(16))) ushort Ks[2][BK * LDK];
    __shared__ __attribute__((aligned(16))) ushort Vt[2][D_ * LDK];
    __shared__ __attribute__((aligned(16))) float  Em[S_];

    const int qt = blockIdx.x, h = blockIdx.y, b = blockIdx.z;
    const int tid = threadIdx.x;
    const int w = tid >> 6, lane = tid & 63, g = lane >> 4, l15 = lane & 15;
    const int gh = g >> 1, glo = g & 1, h3 = l15 >> 3;
    {
        float4 mv = *(const float4*)(maskg + (size_t)b * S_ + tid * 4);
        *(float4*)&Em[tid * 4] = make_float4(mv.x * LOG2E, mv.y * LOG2E,
                                             mv.z * LOG2E, mv.w * LOG2E);
    }
    const int qrow = qt * BQ + w * 16 + l15;
    const float* qp = qg + (size_t)(b * S_ + qrow) * ROWSZ + h * D_;
    bf16x8 qf[2];
#pragma unroll
    for (int half = 0; half < 2; ++half) {
        float4 f0 = *(const float4*)(qp + half * 32 + g * 8);
        float4 f1 = *(const float4*)(qp + half * 32 + g * 8 + 4);
        union { bf16x8 v; uint4 u; } x;
        x.u = make_uint4(pack2(f0.x * SCALE2, f0.y * SCALE2),
                         pack2(f0.z * SCALE2, f0.w * SCALE2),
                         pack2(f1.x * SCALE2, f1.y * SCALE2),
                         pack2(f1.z * SCALE2, f1.w * SCALE2));
        qf[half] = x.v;
    }
    const int skey16 = tid >> 4;
    const int sd4    = (tid & 15) * 4;
    const int svd    = lane;
    const int svk8   = w * 8;
    const int vphys  = (w ^ ((lane >> 3) & 7)) * 8;
    const size_t kvbase = (size_t)b * S_ * ROWSZ + h * D_;
    float4 kpre0, kpre1;
    float  vpre[8];
    auto prefetch = [&](int kt) {
        const float* kbp = kg + kvbase + (size_t)kt * BK * ROWSZ;
        kpre0 = *(const float4*)(kbp + (size_t)skey16 * ROWSZ + sd4);
        kpre1 = *(const float4*)(kbp + (size_t)(skey16 + 32) * ROWSZ + sd4);
        const float* vbp = vg + kvbase + (size_t)kt * BK * ROWSZ + svd;
#pragma unroll
        for (int i = 0; i < 8; ++i) vpre[i] = vbp[(size_t)(svk8 + i) * ROWSZ];
    };
    auto stage = [&](int buf) {
        *(uint2*)&Ks[buf][skey16 * LDK + sd4] =
            make_uint2(pack2(kpre0.x, kpre0.y), pack2(kpre0.z, kpre0.w));
        *(uint2*)&Ks[buf][(skey16 + 32) * LDK + sd4] =
            make_uint2(pack2(kpre1.x, kpre1.y), pack2(kpre1.z, kpre1.w));
        *(uint4*)&Vt[buf][svd * LDK + vphys] =
            make_uint4(pack2(vpre[0], vpre[1]), pack2(vpre[2], vpre[3]),
                       pack2(vpre[4], vpre[5]), pack2(vpre[6], vpre[7]));
    };
    float l_r = 0.0f;
    f32x4 o_acc[4];
#pragma unroll
    for (int t = 0; t < 4; ++t) o_acc[t] = (f32x4){0.f, 0.f, 0.f, 0.f};
    prefetch(0);
    stage(0);
    __syncthreads();
    const int koff  = l15 * LDK + g * 8;
    const int vbase = l15 * LDK + glo * 4;
    for (int kt = 0; kt < NT; ++kt) {
        const int cur = kt & 1;
        if (kt + 1 < NT) prefetch(kt + 1);
        const ushort* ks = Ks[cur];
        float sv[4][4];
#pragma unroll
        for (int t = 0; t < 4; ++t) {
            f32x4 acc = *(const f32x4*)&Em[kt * BK + t * 16 + g * 4];
            bf16x8 kf0 = *(const bf16x8*)&ks[t * 16 * LDK + koff];
            bf16x8 kf1 = *(const bf16x8*)&ks[t * 16 * LDK + koff + 32];
            acc = __builtin_amdgcn_mfma_f32_16x16x32_bf16(kf0, qf[0], acc, 0, 0, 0);
            acc = __builtin_amdgcn_mfma_f32_16x16x32_bf16(kf1, qf[1], acc, 0, 0, 0);
            sv[t][0] = acc[0]; sv[t][1] = acc[1]; sv[t][2] = acc[2]; sv[t][3] = acc[3];
        }
        float rs = 0.f;
#pragma unroll
        for (int t = 0; t < 4; ++t)
#pragma unroll
            for (int r = 0; r < 4; ++r) {
                float p = fexp2(sv[t][r]);
                sv[t][r] = p;
                rs += p;
            }
        l_r += rs;
        bf16x4 pf[4];
#pragma unroll
        for (int c = 0; c < 4; ++c) {
            union { bf16x4 v; uint2 u; } x;
            x.u = make_uint2(pack2(sv[c][0], sv[c][1]), pack2(sv[c][2], sv[c][3]));
            pf[c] = x.v;
        }
        const ushort* vt = Vt[cur];
#pragma unroll
        for (int t2 = 0; t2 < 4; ++t2) {
            const int e = (2 * t2 + h3) & 7;
#pragma unroll
            for (int c = 0; c < 4; ++c) {
                const int physu = (2 * c + gh) ^ e;
                bf16x4 vf = *(const bf16x4*)&vt[t2 * 16 * LDK + vbase + physu * 8];
                o_acc[t2] = mfma16(vf, pf[c], o_acc[t2]);
            }
        }
        if (kt + 1 < NT) stage(cur ^ 1);
        __syncthreads();
    }
    l_r += __shfl_xor(l_r, 16);
    l_r += __shfl_xor(l_r, 32);
    const float inv = 1.0f / l_r;
    float* op = outg + (size_t)(b * S_ + qrow) * ROWSZ + h * D_;
#pragma unroll
    for (int t2 = 0; t2 < 4; ++t2)
#pragma unroll
        for (int r = 0; r < 4; ++r)
            op[t2 * 16 + g * 4 + r] = o_acc[t2][r] * inv;
}

extern "C" void kernel_launch(void* const* d_in, const int* in_sizes, int n_in,
                              void* d_out, int out_size, void* d_ws, size_t ws_size,
                              hipStream_t stream) {
    const float* q    = (const float*)d_in[0];
    const float* k    = (const float*)d_in[1];
    const float* v    = (const float*)d_in[2];
    const float* mask = (const float*)d_in[3];
    float* out = (float*)d_out;

    const size_t elems = (size_t)B_ * H_ * S_ * D_;      // 4.19M per tensor
    const size_t need  = elems * sizeof(ushort) * 2;     // 16.78 MB
    dim3 grid(S_ / BQ, H_, B_);                          // (16,16,2)

    if (ws_size >= need) {
        ushort* kbuf = (ushort*)d_ws;
        ushort* vbuf = kbuf + elems;
        prep_k<<<2048, 256, 0, stream>>>(k, kbuf);
        prep_v<<<1024, 256, 0, stream>>>(v, vbuf);
        fattn_gll<<<grid, dim3(512), 0, stream>>>(q, kbuf, vbuf, mask, out);
    } else {
        fattn_fb<<<grid, dim3(512), 0, stream>>>(q, k, v, mask, out);
    }
}